// Round 1
// baseline (625.053 us; speedup 1.0000x reference)
//
#include <hip/hip_runtime.h>
#include <math.h>

// MoE gate: logits = x[16384,2048] @ W^T[2048,64]; top-8 of logits;
// weights = softmax over the top-8 logits (== softmax-all then renorm).
//
// Layout: block = 512 threads = 8 waves, handles 64 tokens (lane = token).
// Each wave accumulates all 64 experts over a 256-wide H slice; W is read
// via wave-uniform (scalar) loads, x via per-lane float4 loads. LDS tree
// reduce 8->1, wave 0 does top-8 + softmax + store.

#define H_DIM 2048
#define N_EXP 64
#define TOPK 8
#define WAVES_PER_BLK 8
#define TOK_PER_BLK 64
#define H_PER_WAVE (H_DIM / WAVES_PER_BLK) // 256
#define CHUNK 16

__global__ __launch_bounds__(512) void moe_gate_kernel(
    const float* __restrict__ x, const float* __restrict__ w,
    float* __restrict__ out, int n_tokens) {
  const int lane = threadIdx.x & 63;
  const int wave = threadIdx.x >> 6;
  const int t = blockIdx.x * TOK_PER_BLK + lane;

  // Force wave-uniform h offset into an SGPR so W loads become s_load.
  const int h0 = __builtin_amdgcn_readfirstlane(wave * H_PER_WAVE);

  float acc[N_EXP];
#pragma unroll
  for (int e = 0; e < N_EXP; ++e) acc[e] = 0.f;

  const float* xrow = x + (size_t)t * H_DIM;

  for (int c = 0; c < H_PER_WAVE / CHUNK; ++c) {
    const int hb = h0 + c * CHUNK;
    float xv[CHUNK];
    const float4* xp = reinterpret_cast<const float4*>(xrow + hb);
#pragma unroll
    for (int j4 = 0; j4 < CHUNK / 4; ++j4) {
      float4 v = xp[j4];
      xv[j4 * 4 + 0] = v.x;
      xv[j4 * 4 + 1] = v.y;
      xv[j4 * 4 + 2] = v.z;
      xv[j4 * 4 + 3] = v.w;
    }
#pragma unroll
    for (int e = 0; e < N_EXP; ++e) {
      const float* wr = w + e * H_DIM + hb;  // uniform address -> s_load
#pragma unroll
      for (int j = 0; j < CHUNK; ++j) acc[e] = fmaf(xv[j], wr[j], acc[e]);
    }
  }

  // ---- tree reduce partial logits across the 8 waves into wave 0 ----
  __shared__ float red[4 * N_EXP * TOK_PER_BLK];  // 64 KB max round
#pragma unroll
  for (int half = 4; half >= 1; half >>= 1) {
    if (wave >= half && wave < 2 * half) {
#pragma unroll
      for (int e = 0; e < N_EXP; ++e)
        red[((wave - half) * N_EXP + e) * TOK_PER_BLK + lane] = acc[e];
    }
    __syncthreads();
    if (wave < half) {
#pragma unroll
      for (int e = 0; e < N_EXP; ++e)
        acc[e] += red[(wave * N_EXP + e) * TOK_PER_BLK + lane];
    }
    __syncthreads();
  }

  if (wave != 0) return;

  // ---- per-lane top-8 (selection sort; strict > keeps lowest index on tie,
  // matching jax.lax.top_k) ----
  float bw[TOPK];
  int bi[TOPK];
#pragma unroll
  for (int k = 0; k < TOPK; ++k) {
    float m = acc[0];
    int mi = 0;
#pragma unroll
    for (int e = 1; e < N_EXP; ++e) {
      if (acc[e] > m) {
        m = acc[e];
        mi = e;
      }
    }
    bw[k] = m;
    bi[k] = mi;
#pragma unroll
    for (int e = 0; e < N_EXP; ++e)
      if (e == mi) acc[e] = -INFINITY;
  }

  // softmax over top-8 == softmax-all-then-renormalize (exact in real math)
  const float mx = bw[0];
  float ew[TOPK];
  float s = 0.f;
#pragma unroll
  for (int k = 0; k < TOPK; ++k) {
    ew[k] = expf(bw[k] - mx);
    s += ew[k];
  }
  const float inv = 1.f / s;

  float4 w0, w1, i0, i1;
  w0.x = ew[0] * inv; w0.y = ew[1] * inv; w0.z = ew[2] * inv; w0.w = ew[3] * inv;
  w1.x = ew[4] * inv; w1.y = ew[5] * inv; w1.z = ew[6] * inv; w1.w = ew[7] * inv;
  i0.x = (float)bi[0]; i0.y = (float)bi[1]; i0.z = (float)bi[2]; i0.w = (float)bi[3];
  i1.x = (float)bi[4]; i1.y = (float)bi[5]; i1.z = (float)bi[6]; i1.w = (float)bi[7];

  float4* ow = reinterpret_cast<float4*>(out + (size_t)t * TOPK);
  ow[0] = w0;
  ow[1] = w1;
  float4* oi =
      reinterpret_cast<float4*>(out + (size_t)n_tokens * TOPK + (size_t)t * TOPK);
  oi[0] = i0;
  oi[1] = i1;
}

extern "C" void kernel_launch(void* const* d_in, const int* in_sizes, int n_in,
                              void* d_out, int out_size, void* d_ws,
                              size_t ws_size, hipStream_t stream) {
  const float* x = (const float*)d_in[0];
  const float* w = (const float*)d_in[1];
  float* out = (float*)d_out;
  const int n_tokens = in_sizes[0] / H_DIM;  // 16384
  const int n_blocks = n_tokens / TOK_PER_BLK;  // 256
  moe_gate_kernel<<<n_blocks, 512, 0, stream>>>(x, w, out, n_tokens);
}

// Round 2
// 345.981 us; speedup vs baseline: 1.8066x; 1.8066x over previous
//
#include <hip/hip_runtime.h>
#include <math.h>

// MoE gate: logits = x[16384,2048] @ W^T[2048,64]; top-8; softmax over top-8.
//
// Round-2 structure (fixes round-1 acc[64] scratch spill, WRITE_SIZE 37MB):
//   grid  = 256 blocks (64 tokens each), block = 1024 thr = 16 waves.
//   wave  = (expert-group eg in [0,4)) x (h-slice hs in [0,4))
//           -> acc[16] per lane (lane = token), 512-wide H slice.
//   Reduce h-slices via LDS atomicAdd into logits[64][64] (16 KB).
//   Wave 0: per-lane top-8 (strict >, matches lax.top_k ties) + softmax.
// Occupancy: 4096 waves = 4 waves/SIMD; launch_bounds caps VGPR at 128.

#define H_DIM 2048
#define N_EXP 64
#define TOPK 8
#define TOK_PER_BLK 64
#define EG 4                          // expert groups per block
#define E_PER_WAVE (N_EXP / EG)       // 16
#define HS 4                          // h slices per block
#define H_PER_WAVE (H_DIM / HS)       // 512
#define CHUNK 16

__global__ __launch_bounds__(1024, 4) void moe_gate_kernel(
    const float* __restrict__ x, const float* __restrict__ w,
    float* __restrict__ out, int n_tokens) {
  __shared__ float logits[N_EXP * TOK_PER_BLK];  // [e][tok], 16 KB

  const int lane = threadIdx.x & 63;
  const int wave = threadIdx.x >> 6;
  const int t = blockIdx.x * TOK_PER_BLK + lane;

  // zero the logits tile (harness poisons LDS-adjacent ws, LDS starts undef)
  for (int i = threadIdx.x; i < N_EXP * TOK_PER_BLK; i += 1024)
    logits[i] = 0.f;
  __syncthreads();

  // wave-uniform expert-group / h-slice, forced into SGPRs
  const int eg = __builtin_amdgcn_readfirstlane(wave & (EG - 1));
  const int hs = __builtin_amdgcn_readfirstlane(wave >> 2);
  const int e0 = eg * E_PER_WAVE;
  const int h0 = hs * H_PER_WAVE;

  float acc[E_PER_WAVE];
#pragma unroll
  for (int e = 0; e < E_PER_WAVE; ++e) acc[e] = 0.f;

  const float* xrow = x + (size_t)t * H_DIM + h0;

  for (int c = 0; c < H_PER_WAVE / CHUNK; ++c) {
    float xv[CHUNK];
    const float4* xp = reinterpret_cast<const float4*>(xrow + c * CHUNK);
#pragma unroll
    for (int j4 = 0; j4 < CHUNK / 4; ++j4) {
      float4 v = xp[j4];
      xv[j4 * 4 + 0] = v.x;
      xv[j4 * 4 + 1] = v.y;
      xv[j4 * 4 + 2] = v.z;
      xv[j4 * 4 + 3] = v.w;
    }
#pragma unroll
    for (int e = 0; e < E_PER_WAVE; ++e) {
      // uniform address (e0,h0,c all wave-uniform) -> scalar loads
      const float* wr = w + (size_t)(e0 + e) * H_DIM + h0 + c * CHUNK;
#pragma unroll
      for (int j = 0; j < CHUNK; ++j) acc[e] = fmaf(xv[j], wr[j], acc[e]);
    }
  }

  // reduce the 4 h-slice partials per (expert, token) via LDS float atomics
#pragma unroll
  for (int e = 0; e < E_PER_WAVE; ++e)
    atomicAdd(&logits[(e0 + e) * TOK_PER_BLK + lane], acc[e]);
  __syncthreads();

  if (wave != 0) return;

  // ---- wave 0: per-lane top-8 over 64 logits (lane = token) ----
  float lg[N_EXP];
#pragma unroll
  for (int e = 0; e < N_EXP; ++e) lg[e] = logits[e * TOK_PER_BLK + lane];

  float bw[TOPK];
  int bi[TOPK];
#pragma unroll
  for (int k = 0; k < TOPK; ++k) {
    float m = lg[0];
    int mi = 0;
#pragma unroll
    for (int e = 1; e < N_EXP; ++e) {
      if (lg[e] > m) {  // strict > keeps lowest index on tie (lax.top_k)
        m = lg[e];
        mi = e;
      }
    }
    bw[k] = m;
    bi[k] = mi;
#pragma unroll
    for (int e = 0; e < N_EXP; ++e)
      if (e == mi) lg[e] = -INFINITY;
  }

  // softmax over top-8 == full softmax renormalized to top-8 (exact)
  const float mx = bw[0];
  float ew[TOPK];
  float s = 0.f;
#pragma unroll
  for (int k = 0; k < TOPK; ++k) {
    ew[k] = expf(bw[k] - mx);
    s += ew[k];
  }
  const float inv = 1.f / s;

  float4 w0, w1, i0, i1;
  w0.x = ew[0] * inv; w0.y = ew[1] * inv; w0.z = ew[2] * inv; w0.w = ew[3] * inv;
  w1.x = ew[4] * inv; w1.y = ew[5] * inv; w1.z = ew[6] * inv; w1.w = ew[7] * inv;
  i0.x = (float)bi[0]; i0.y = (float)bi[1]; i0.z = (float)bi[2]; i0.w = (float)bi[3];
  i1.x = (float)bi[4]; i1.y = (float)bi[5]; i1.z = (float)bi[6]; i1.w = (float)bi[7];

  float4* ow = reinterpret_cast<float4*>(out + (size_t)t * TOPK);
  ow[0] = w0;
  ow[1] = w1;
  float4* oi =
      reinterpret_cast<float4*>(out + (size_t)n_tokens * TOPK + (size_t)t * TOPK);
  oi[0] = i0;
  oi[1] = i1;
}

extern "C" void kernel_launch(void* const* d_in, const int* in_sizes, int n_in,
                              void* d_out, int out_size, void* d_ws,
                              size_t ws_size, hipStream_t stream) {
  const float* x = (const float*)d_in[0];
  const float* w = (const float*)d_in[1];
  float* out = (float*)d_out;
  const int n_tokens = in_sizes[0] / H_DIM;        // 16384
  const int n_blocks = n_tokens / TOK_PER_BLK;     // 256
  moe_gate_kernel<<<n_blocks, 1024, 0, stream>>>(x, w, out, n_tokens);
}